// Round 2
// baseline (111.637 us; speedup 1.0000x reference)
//
#include <hip/hip_runtime.h>
#include <hip/hip_bf16.h>

// Reference returns `inputs` unchanged (ScaleGrad.forward is identity; the
// counts/weights only affect backward, not benched). Pure D2D copy of
// d_in[0] (float32, 16384*4096 = 67,108,864 elems = 256 MiB) into d_out.
//
// Round 1: hipMemcpyAsync = 104.6 us (~5.1 TB/s). Custom float4 grid-stride
// copy measured at 6.29 TB/s on MI355X (learn_hip m13) -> target ~85 us.

__global__ __launch_bounds__(256) void copy_f4_kernel(const float4* __restrict__ in,
                                                      float4* __restrict__ out,
                                                      int n4) {
    int stride = gridDim.x * blockDim.x;
    for (int i = blockIdx.x * blockDim.x + threadIdx.x; i < n4; i += stride) {
        out[i] = in[i];
    }
}

extern "C" void kernel_launch(void* const* d_in, const int* in_sizes, int n_in,
                              void* d_out, int out_size, void* d_ws, size_t ws_size,
                              hipStream_t stream) {
    const float4* inputs = (const float4*)d_in[0];
    float4* out = (float4*)d_out;
    int n4 = out_size / 4;  // 16,777,216 float4s (out_size divisible by 4)
    // Memory-bound: cap grid at ~8 blocks/CU * 256 CUs, grid-stride the rest.
    int blocks = 2048;
    copy_f4_kernel<<<blocks, 256, 0, stream>>>(inputs, out, n4);
}

// Round 4
// 92.138 us; speedup vs baseline: 1.2116x; 1.2116x over previous
//
#include <hip/hip_runtime.h>
#include <hip/hip_bf16.h>

// Reference returns `inputs` unchanged (ScaleGrad.forward is identity; the
// counts/weights only affect backward, not benched). Pure D2D copy of
// d_in[0] (float32, 16384*4096 = 67,108,864 elems = 256 MiB) into d_out.
//
// R1: hipMemcpyAsync = 104.6 us (~5.1 TB/s).
// R2: float4 grid-stride, 2048 blocks = 111.6 us (~4.8 TB/s) — regressed.
// R3: nontemporal builtins reject HIP_vector_type — use clang ext_vector.
// R4: 4x-unrolled 16B copy (4 loads in flight) + nontemporal, exact grid.

typedef float vfloat4 __attribute__((ext_vector_type(4)));

__global__ __launch_bounds__(256) void copy_f4x4_kernel(const vfloat4* __restrict__ in,
                                                        vfloat4* __restrict__ out) {
    // Each block copies 1024 float4s (16 KiB); each thread 4 float4s spaced
    // by 256 so every access is wave-coalesced.
    int base = blockIdx.x * 1024 + threadIdx.x;
    vfloat4 a = __builtin_nontemporal_load(&in[base]);
    vfloat4 b = __builtin_nontemporal_load(&in[base + 256]);
    vfloat4 c = __builtin_nontemporal_load(&in[base + 512]);
    vfloat4 d = __builtin_nontemporal_load(&in[base + 768]);
    __builtin_nontemporal_store(a, &out[base]);
    __builtin_nontemporal_store(b, &out[base + 256]);
    __builtin_nontemporal_store(c, &out[base + 512]);
    __builtin_nontemporal_store(d, &out[base + 768]);
}

extern "C" void kernel_launch(void* const* d_in, const int* in_sizes, int n_in,
                              void* d_out, int out_size, void* d_ws, size_t ws_size,
                              hipStream_t stream) {
    const vfloat4* inputs = (const vfloat4*)d_in[0];
    vfloat4* out = (vfloat4*)d_out;
    int n4 = out_size / 4;       // 16,777,216 float4s
    int blocks = n4 / 1024;      // 16,384 blocks, exact (out_size = 2^26)
    copy_f4x4_kernel<<<blocks, 256, 0, stream>>>(inputs, out);
}

// Round 5
// 90.100 us; speedup vs baseline: 1.2390x; 1.0226x over previous
//
#include <hip/hip_runtime.h>
#include <hip/hip_bf16.h>

// Reference returns `inputs` unchanged (ScaleGrad.forward is identity; the
// counts/weights only affect backward, not benched). Pure D2D copy of
// d_in[0] (float32, 16384*4096 = 67,108,864 elems = 256 MiB) into d_out.
//
// R1: hipMemcpyAsync = 104.6 us (~5.1 TB/s).
// R2: float4 grid-stride, 2048 blocks = 111.6 us (~4.8 TB/s).
// R4: 4x-unrolled nontemporal float4, 16384 blocks = 92.1 us (~5.8 TB/s).
// R5: 8x-unrolled (8 loads in flight/thread), 8192 blocks — chase 6.29 TB/s
//     measured copy ceiling (85.4 us floor).

typedef float vfloat4 __attribute__((ext_vector_type(4)));

__global__ __launch_bounds__(256) void copy_f4x8_kernel(const vfloat4* __restrict__ in,
                                                        vfloat4* __restrict__ out) {
    // Each block copies 2048 float4s (32 KiB); each thread 8 float4s spaced
    // by 256 so every access is wave-coalesced.
    int base = blockIdx.x * 2048 + threadIdx.x;
    vfloat4 r0 = __builtin_nontemporal_load(&in[base]);
    vfloat4 r1 = __builtin_nontemporal_load(&in[base + 256]);
    vfloat4 r2 = __builtin_nontemporal_load(&in[base + 512]);
    vfloat4 r3 = __builtin_nontemporal_load(&in[base + 768]);
    vfloat4 r4 = __builtin_nontemporal_load(&in[base + 1024]);
    vfloat4 r5 = __builtin_nontemporal_load(&in[base + 1280]);
    vfloat4 r6 = __builtin_nontemporal_load(&in[base + 1536]);
    vfloat4 r7 = __builtin_nontemporal_load(&in[base + 1792]);
    __builtin_nontemporal_store(r0, &out[base]);
    __builtin_nontemporal_store(r1, &out[base + 256]);
    __builtin_nontemporal_store(r2, &out[base + 512]);
    __builtin_nontemporal_store(r3, &out[base + 768]);
    __builtin_nontemporal_store(r4, &out[base + 1024]);
    __builtin_nontemporal_store(r5, &out[base + 1280]);
    __builtin_nontemporal_store(r6, &out[base + 1536]);
    __builtin_nontemporal_store(r7, &out[base + 1792]);
}

extern "C" void kernel_launch(void* const* d_in, const int* in_sizes, int n_in,
                              void* d_out, int out_size, void* d_ws, size_t ws_size,
                              hipStream_t stream) {
    const vfloat4* inputs = (const vfloat4*)d_in[0];
    vfloat4* out = (vfloat4*)d_out;
    int n4 = out_size / 4;       // 16,777,216 float4s
    int blocks = n4 / 2048;      // 8,192 blocks, exact (out_size = 2^26)
    copy_f4x8_kernel<<<blocks, 256, 0, stream>>>(inputs, out);
}